// Round 1
// baseline (108.912 us; speedup 1.0000x reference)
//
#include <hip/hip_runtime.h>
#include <math.h>

// Problem constants (from reference): B,Q,K,C,OUT,H = 8,1024,1024,16,32,16; WINDOW=0.25
#define BB 8
#define QQ 1024
#define KK 1024
#define CC 16
#define NS 2048                 // table intervals over d in [0, 0.25]
#define TSTRIDE (NS + 2)        // per-channel stride (pad)

// ---------------------------------------------------------------------------
// Kernel 1: blocks 0..7  -> bucket keys of batch b by channel, gather values
//           blocks 8..   -> build w = f(d, c) lookup table (the scalar MLP)
// w(d,c) = |W3 . relu(W2 . relu(W1 . relu(d*W0[:,0] + W0[:,1+c] + b0) + b1) + b2) + b3|
// ---------------------------------------------------------------------------
__global__ __launch_bounds__(256) void prep_kernel(
    const float* __restrict__ keys_in, const float* __restrict__ values,
    const float* __restrict__ W0, const float* __restrict__ b0,
    const float* __restrict__ W1, const float* __restrict__ b1,
    const float* __restrict__ W2, const float* __restrict__ b2,
    const float* __restrict__ W3, const float* __restrict__ b3,
    float* __restrict__ tbl, float* __restrict__ pos_b,
    float* __restrict__ val_b, int* __restrict__ offs_b)
{
  const int tid = threadIdx.x;
  const int blk = blockIdx.x;

  if (blk < BB) {
    // ---- bucket batch `blk` by channel ----
    __shared__ int cnt[CC];
    __shared__ int offs[CC + 1];
    __shared__ int cur[CC];
    if (tid < CC) cnt[tid] = 0;
    __syncthreads();
    for (int k = tid; k < KK; k += 256) {
      int c = (int)keys_in[blk * (2 * KK) + 2 * k];
      atomicAdd(&cnt[c], 1);
    }
    __syncthreads();
    if (tid == 0) {
      int s = 0;
      for (int c = 0; c < CC; ++c) { offs[c] = s; cur[c] = s; s += cnt[c]; }
      offs[CC] = s;  // == 1024
    }
    __syncthreads();
    for (int k = tid; k < KK; k += 256) {
      int c = (int)keys_in[blk * (2 * KK) + 2 * k];
      float p = keys_in[blk * (2 * KK) + 2 * k + 1];
      int idx = atomicAdd(&cur[c], 1);
      pos_b[blk * KK + idx] = p;
      val_b[blk * KK + idx] = values[(blk * KK + k) * CC + c];
    }
    __syncthreads();
    if (tid < CC + 1) offs_b[blk * 32 + tid] = offs[tid];
  } else {
    // ---- build f(d,c) table ----
    __shared__ float sW0p[16];      // W0[i,0]
    __shared__ float sH[256];       // hoh[c][i] = W0[i,1+c] + b0[i]
    __shared__ float sW1[256], sb1[16], sW2[256], sb2[16], sW3[16], sb3[1];
    if (tid < 16) {
      sW0p[tid] = W0[tid * 17];
      sb1[tid]  = b1[tid];
      sb2[tid]  = b2[tid];
      sW3[tid]  = W3[tid];
    }
    if (tid == 0) sb3[0] = b3[0];
    {
      int i = tid >> 4, c = tid & 15;
      sH[c * 16 + i] = W0[i * 17 + 1 + c] + b0[i];
      sW1[tid] = W1[tid];
      sW2[tid] = W2[tid];
    }
    __syncthreads();

    const int total = CC * (NS + 1);
    const int stride = (gridDim.x - BB) * 256;
    for (int e = (blk - BB) * 256 + tid; e < total; e += stride) {
      int c = e / (NS + 1);
      int s = e - c * (NS + 1);
      float d = (float)s * (0.25f / (float)NS);
      float h0[16], h1[16];
#pragma unroll
      for (int i = 0; i < 16; ++i) {
        float v = fmaf(d, sW0p[i], sH[c * 16 + i]);
        h0[i] = v > 0.f ? v : 0.f;
      }
#pragma unroll
      for (int j = 0; j < 16; ++j) {
        float a = sb1[j];
#pragma unroll
        for (int i = 0; i < 16; ++i) a = fmaf(sW1[j * 16 + i], h0[i], a);
        h1[j] = a > 0.f ? a : 0.f;
      }
      float w = sb3[0];
#pragma unroll
      for (int j = 0; j < 16; ++j) {
        float a = sb2[j];
#pragma unroll
        for (int i = 0; i < 16; ++i) a = fmaf(sW2[j * 16 + i], h1[i], a);
        a = a > 0.f ? a : 0.f;
        w = fmaf(sW3[j], a, w);
      }
      tbl[c * TSTRIDE + s] = fabsf(w);
    }
  }
}

// ---------------------------------------------------------------------------
// Kernel 2: one wave per query. lane = (c = lane&15, h = lane>>4); each lane
// walks 1/4 of channel-c's bucket, lerps w from the table (L2-resident),
// accumulates den/num; shfl_xor reduce; 32x32 output head from padded LDS.
// ---------------------------------------------------------------------------
__global__ __launch_bounds__(256) void main_kernel(
    const float* __restrict__ queries,
    const float* __restrict__ Wd, const float* __restrict__ bd,
    const float* __restrict__ Wr, const float* __restrict__ br,
    const float* __restrict__ tbl, const float* __restrict__ pos_b,
    const float* __restrict__ val_b, const int* __restrict__ offs_b,
    float* __restrict__ out)
{
  __shared__ float pos_s[KK];
  __shared__ float val_s[KK];
  __shared__ int   offs_s[CC + 1];
  __shared__ float wr_s[32 * 33];   // padded stride 33 to avoid bank conflicts
  __shared__ float br_s[32];
  __shared__ float ep_s[4][33];     // [wave][targets(16) | dens(16)]
  __shared__ float wdbd[2];

  const int tid = threadIdx.x;
  const int b  = blockIdx.x >> 8;   // 256 blocks per batch
  const int qt = blockIdx.x & 255;  // 4 queries per block (1 per wave)

  for (int k = tid; k < KK; k += 256) {
    pos_s[k] = pos_b[b * KK + k];
    val_s[k] = val_b[b * KK + k];
  }
  if (tid < CC + 1) offs_s[tid] = offs_b[b * 32 + tid];
  { // Wr (32x32) into padded LDS
    int o = tid >> 5, j = tid & 31;
    wr_s[o * 33 + j] = Wr[tid];                 // rows 0..7
    wr_s[(o + 8) * 33 + j]  = Wr[tid + 256];    // rows 8..15
    wr_s[(o + 16) * 33 + j] = Wr[tid + 512];    // rows 16..23
    wr_s[(o + 24) * 33 + j] = Wr[tid + 768];    // rows 24..31
  }
  if (tid < 32) br_s[tid] = br[tid];
  if (tid == 0) { wdbd[0] = Wd[0]; wdbd[1] = bd[0]; }
  __syncthreads();

  const int wave = tid >> 6;
  const int lane = tid & 63;
  const int q = qt * 4 + wave;
  const float qpos = queries[b * QQ + q];
  const int c = lane & 15;
  const int h = lane >> 4;          // 0..3: quarter of the bucket

  const float* __restrict__ tc = tbl + c * TSTRIDE;
  float den = 0.f, num = 0.f;
  const int kend = offs_s[c + 1];
  for (int k = offs_s[c] + h; k < kend; k += 4) {
    float p = pos_s[k];
    float d = fabsf(p - qpos);
    if (d < 0.25f) {
      float t = d * ((float)NS / 0.25f);
      int   i = (int)t;
      float f = t - (float)i;
      float t0 = tc[i];
      float t1 = tc[i + 1];
      float w  = fmaf(t1 - t0, f, t0);
      den += w;
      num  = fmaf(w, val_s[k], num);
    }
  }
  // reduce the 4 quarter-bucket partials (lanes differing in bits 4,5)
  den += __shfl_xor(den, 16, 64);
  num += __shfl_xor(num, 16, 64);
  den += __shfl_xor(den, 32, 64);
  num += __shfl_xor(num, 32, 64);

  if (h == 0) {
    float tgt = num / (den + 1e-5f);
    float x   = fmaf(fmaf(den, 0.1f, -1.0f), wdbd[0], wdbd[1]);
    float dn  = 1.0f / (1.0f + expf(-x));
    ep_s[wave][c]      = tgt;
    ep_s[wave][16 + c] = dn;
  }
  __syncthreads();

  if (lane < 32) {
    const int o = lane;
    float acc = br_s[o];
#pragma unroll
    for (int j = 0; j < 32; ++j)
      acc = fmaf(ep_s[wave][j], wr_s[o * 33 + j], acc);
    out[(b * QQ + q) * 32 + o] = acc;
  }
}

extern "C" void kernel_launch(void* const* d_in, const int* in_sizes, int n_in,
                              void* d_out, int out_size, void* d_ws, size_t ws_size,
                              hipStream_t stream) {
  const float* keys_in = (const float*)d_in[0];
  const float* queries = (const float*)d_in[1];
  const float* values  = (const float*)d_in[2];
  const float* W0 = (const float*)d_in[3];
  const float* b0 = (const float*)d_in[4];
  const float* W1 = (const float*)d_in[5];
  const float* b1 = (const float*)d_in[6];
  const float* W2 = (const float*)d_in[7];
  const float* b2 = (const float*)d_in[8];
  const float* W3 = (const float*)d_in[9];
  const float* b3 = (const float*)d_in[10];
  const float* Wd = (const float*)d_in[11];
  const float* bd = (const float*)d_in[12];
  const float* Wr = (const float*)d_in[13];
  const float* br = (const float*)d_in[14];
  float* out = (float*)d_out;

  // workspace layout (~198 KB total)
  float* tbl   = (float*)d_ws;                  // 16 * TSTRIDE floats
  float* pos_b = tbl + CC * TSTRIDE;            // 8 * 1024
  float* val_b = pos_b + BB * KK;               // 8 * 1024
  int*   offs_b = (int*)(val_b + BB * KK);      // 8 * 32

  prep_kernel<<<BB + 128, 256, 0, stream>>>(keys_in, values, W0, b0, W1, b1,
                                            W2, b2, W3, b3, tbl, pos_b, val_b, offs_b);
  main_kernel<<<2048, 256, 0, stream>>>(queries, Wd, bd, Wr, br,
                                        tbl, pos_b, val_b, offs_b, out);
}

// Round 2
// 107.193 us; speedup vs baseline: 1.0160x; 1.0160x over previous
//
#include <hip/hip_runtime.h>
#include <math.h>

// Problem constants (from reference): B,Q,K,C,OUT,H = 8,1024,1024,16,32,16; WINDOW=0.25
#define BB 8
#define QQ 1024
#define KK 1024
#define CC 16
#define NS 512                  // table intervals over d in [0, 0.25]  (f is piecewise-linear -> lerp err ~ NS^-1)
#define TSTRIDE (NS + 1)        // 513 per-channel stride; 513 % 32 == 1 -> channel bases hit distinct banks
#define TFLOATS (CC * TSTRIDE)  // 8208 floats = 32832 B = 2052 float4

// ---------------------------------------------------------------------------
// Kernel 1: blocks 0..7  -> bucket keys of batch b by channel, gather values
//           blocks 8..   -> build w = f(d, c) lookup table (the scalar MLP)
// w(d,c) = |W3 . relu(W2 . relu(W1 . relu(d*W0[:,0] + W0[:,1+c] + b0) + b1) + b2) + b3|
// ---------------------------------------------------------------------------
__global__ __launch_bounds__(256) void prep_kernel(
    const float* __restrict__ keys_in, const float* __restrict__ values,
    const float* __restrict__ W0, const float* __restrict__ b0,
    const float* __restrict__ W1, const float* __restrict__ b1,
    const float* __restrict__ W2, const float* __restrict__ b2,
    const float* __restrict__ W3, const float* __restrict__ b3,
    float* __restrict__ tbl, float* __restrict__ pos_b,
    float* __restrict__ val_b, int* __restrict__ offs_b)
{
  const int tid = threadIdx.x;
  const int blk = blockIdx.x;

  if (blk < BB) {
    // ---- bucket batch `blk` by channel ----
    __shared__ int cnt[CC];
    __shared__ int offs[CC + 1];
    __shared__ int cur[CC];
    if (tid < CC) cnt[tid] = 0;
    __syncthreads();
    for (int k = tid; k < KK; k += 256) {
      int c = (int)keys_in[blk * (2 * KK) + 2 * k];
      atomicAdd(&cnt[c], 1);
    }
    __syncthreads();
    if (tid == 0) {
      int s = 0;
      for (int c = 0; c < CC; ++c) { offs[c] = s; cur[c] = s; s += cnt[c]; }
      offs[CC] = s;  // == 1024
    }
    __syncthreads();
    for (int k = tid; k < KK; k += 256) {
      int c = (int)keys_in[blk * (2 * KK) + 2 * k];
      float p = keys_in[blk * (2 * KK) + 2 * k + 1];
      int idx = atomicAdd(&cur[c], 1);
      pos_b[blk * KK + idx] = p;
      val_b[blk * KK + idx] = values[(blk * KK + k) * CC + c];
    }
    __syncthreads();
    if (tid < CC + 1) offs_b[blk * 32 + tid] = offs[tid];
  } else {
    // ---- build f(d,c) table ----
    __shared__ float sW0p[16];      // W0[i,0]
    __shared__ float sH[256];       // hoh[c][i] = W0[i,1+c] + b0[i]
    __shared__ float sW1[256], sb1[16], sW2[256], sb2[16], sW3[16], sb3[1];
    if (tid < 16) {
      sW0p[tid] = W0[tid * 17];
      sb1[tid]  = b1[tid];
      sb2[tid]  = b2[tid];
      sW3[tid]  = W3[tid];
    }
    if (tid == 0) sb3[0] = b3[0];
    {
      int i = tid >> 4, c = tid & 15;
      sH[c * 16 + i] = W0[i * 17 + 1 + c] + b0[i];
      sW1[tid] = W1[tid];
      sW2[tid] = W2[tid];
    }
    __syncthreads();

    const int total = CC * (NS + 1);
    const int stride = (gridDim.x - BB) * 256;
    for (int e = (blk - BB) * 256 + tid; e < total; e += stride) {
      int c = e / (NS + 1);
      int s = e - c * (NS + 1);
      float d = (float)s * (0.25f / (float)NS);
      float h0[16], h1[16];
#pragma unroll
      for (int i = 0; i < 16; ++i) {
        float v = fmaf(d, sW0p[i], sH[c * 16 + i]);
        h0[i] = v > 0.f ? v : 0.f;
      }
#pragma unroll
      for (int j = 0; j < 16; ++j) {
        float a = sb1[j];
#pragma unroll
        for (int i = 0; i < 16; ++i) a = fmaf(sW1[j * 16 + i], h0[i], a);
        h1[j] = a > 0.f ? a : 0.f;
      }
      float w = sb3[0];
#pragma unroll
      for (int j = 0; j < 16; ++j) {
        float a = sb2[j];
#pragma unroll
        for (int i = 0; i < 16; ++i) a = fmaf(sW2[j * 16 + i], h1[i], a);
        a = a > 0.f ? a : 0.f;
        w = fmaf(sW3[j], a, w);
      }
      tbl[c * TSTRIDE + s] = fabsf(w);
    }
  }
}

// ---------------------------------------------------------------------------
// Kernel 2: one wave per query. lane = (c = lane&15, h = lane>>4); each lane
// walks 1/4 of channel-c's bucket. The full f(d,c) table lives in LDS
// (32.8 KB), so the inner loop is pure LDS+VALU (no global access, no
// divergent branch -> predicated cndmask). 32x32 output head from padded LDS.
// LDS/block ~45 KB -> 3 blocks/CU, 12 waves/CU.
// ---------------------------------------------------------------------------
__global__ __launch_bounds__(256) void main_kernel(
    const float* __restrict__ queries,
    const float* __restrict__ Wd, const float* __restrict__ bd,
    const float* __restrict__ Wr, const float* __restrict__ br,
    const float* __restrict__ tbl, const float* __restrict__ pos_b,
    const float* __restrict__ val_b, const int* __restrict__ offs_b,
    float* __restrict__ out)
{
  __shared__ float4 tls4[TFLOATS / 4];   // 2052 float4 = full f(d,c) table
  __shared__ float pos_s[KK];
  __shared__ float val_s[KK];
  __shared__ int   offs_s[CC + 1];
  __shared__ float wr_s[32 * 33];   // padded stride 33 to avoid bank conflicts
  __shared__ float br_s[32];
  __shared__ float ep_s[4][33];     // [wave][targets(16) | dens(16)]
  __shared__ float wdbd[2];
  float* tls = (float*)tls4;

  const int tid = threadIdx.x;
  const int b  = blockIdx.x >> 8;   // 256 blocks per batch
  const int qt = blockIdx.x & 255;  // 4 queries per block (1 per wave)

  // stage full table (flat float4 copy; global layout matches LDS layout)
  for (int i = tid; i < TFLOATS / 4; i += 256)
    tls4[i] = ((const float4*)tbl)[i];
  for (int k = tid; k < KK; k += 256) {
    pos_s[k] = pos_b[b * KK + k];
    val_s[k] = val_b[b * KK + k];
  }
  if (tid < CC + 1) offs_s[tid] = offs_b[b * 32 + tid];
  { // Wr (32x32) into padded LDS
    int o = tid >> 5, j = tid & 31;
    wr_s[o * 33 + j] = Wr[tid];                 // rows 0..7
    wr_s[(o + 8) * 33 + j]  = Wr[tid + 256];    // rows 8..15
    wr_s[(o + 16) * 33 + j] = Wr[tid + 512];    // rows 16..23
    wr_s[(o + 24) * 33 + j] = Wr[tid + 768];    // rows 24..31
  }
  if (tid < 32) br_s[tid] = br[tid];
  if (tid == 0) { wdbd[0] = Wd[0]; wdbd[1] = bd[0]; }
  __syncthreads();

  const int wave = tid >> 6;
  const int lane = tid & 63;
  const int q = qt * 4 + wave;
  const float qpos = queries[b * QQ + q];
  const int c = lane & 15;
  const int h = lane >> 4;          // 0..3: quarter of the bucket

  const float* __restrict__ tc = tls + c * TSTRIDE;
  float den = 0.f, num = 0.f;
  const int kend = offs_s[c + 1];
#pragma unroll 4
  for (int k = offs_s[c] + h; k < kend; k += 4) {
    float p = pos_s[k];
    float v = val_s[k];
    float d = fabsf(p - qpos);
    float t = d * ((float)NS / 0.25f);
    int   i = (int)t;
    i = i < NS - 1 ? i : NS - 1;    // clamp (predicated path may have d >= 0.25)
    float f = t - (float)i;
    float t0 = tc[i];
    float t1 = tc[i + 1];
    float w  = fmaf(t1 - t0, f, t0);
    w = (d < 0.25f) ? w : 0.0f;     // predicate instead of branch
    den += w;
    num  = fmaf(w, v, num);
  }
  // reduce the 4 quarter-bucket partials (lanes differing in bits 4,5)
  den += __shfl_xor(den, 16, 64);
  num += __shfl_xor(num, 16, 64);
  den += __shfl_xor(den, 32, 64);
  num += __shfl_xor(num, 32, 64);

  if (h == 0) {
    float tgt = num / (den + 1e-5f);
    float x   = fmaf(fmaf(den, 0.1f, -1.0f), wdbd[0], wdbd[1]);
    float dn  = 1.0f / (1.0f + expf(-x));
    ep_s[wave][c]      = tgt;
    ep_s[wave][16 + c] = dn;
  }
  __syncthreads();

  if (lane < 32) {
    const int o = lane;
    float acc = br_s[o];
#pragma unroll
    for (int j = 0; j < 32; ++j)
      acc = fmaf(ep_s[wave][j], wr_s[o * 33 + j], acc);
    out[(b * QQ + q) * 32 + o] = acc;
  }
}

extern "C" void kernel_launch(void* const* d_in, const int* in_sizes, int n_in,
                              void* d_out, int out_size, void* d_ws, size_t ws_size,
                              hipStream_t stream) {
  const float* keys_in = (const float*)d_in[0];
  const float* queries = (const float*)d_in[1];
  const float* values  = (const float*)d_in[2];
  const float* W0 = (const float*)d_in[3];
  const float* b0 = (const float*)d_in[4];
  const float* W1 = (const float*)d_in[5];
  const float* b1 = (const float*)d_in[6];
  const float* W2 = (const float*)d_in[7];
  const float* b2 = (const float*)d_in[8];
  const float* W3 = (const float*)d_in[9];
  const float* b3 = (const float*)d_in[10];
  const float* Wd = (const float*)d_in[11];
  const float* bd = (const float*)d_in[12];
  const float* Wr = (const float*)d_in[13];
  const float* br = (const float*)d_in[14];
  float* out = (float*)d_out;

  // workspace layout (tbl must stay 16B-aligned for float4 staging)
  float* tbl   = (float*)d_ws;                  // TFLOATS floats (32832 B)
  float* pos_b = tbl + TFLOATS;                 // 8 * 1024
  float* val_b = pos_b + BB * KK;               // 8 * 1024
  int*   offs_b = (int*)(val_b + BB * KK);      // 8 * 32

  prep_kernel<<<BB + 128, 256, 0, stream>>>(keys_in, values, W0, b0, W1, b1,
                                            W2, b2, W3, b3, tbl, pos_b, val_b, offs_b);
  main_kernel<<<2048, 256, 0, stream>>>(queries, Wd, bd, Wr, br,
                                        tbl, pos_b, val_b, offs_b, out);
}

// Round 3
// 99.538 us; speedup vs baseline: 1.0942x; 1.0769x over previous
//
#include <hip/hip_runtime.h>
#include <math.h>

// Problem constants (from reference): B,Q,K,C,OUT,H = 8,1024,1024,16,32,16; WINDOW=0.25
#define BB 8
#define QQ 1024
#define KK 1024
#define CC 16
#define NS 512                  // table intervals over d in [0, 0.25]
#define TSTRIDE (NS + 1)        // 513; 513 % 32 == 1 -> channel bases hit distinct banks
#define TFLOATS (CC * TSTRIDE)  // 8208 floats = 32832 B (16B-divisible)
#define NQ 8                    // queries per wave

// ---------------------------------------------------------------------------
// Kernel 1: blocks 0..7  -> bucket keys of batch b by channel, gather values
//           blocks 8..   -> build w = f(d, c) lookup table (the scalar MLP)
// ---------------------------------------------------------------------------
__global__ __launch_bounds__(256) void prep_kernel(
    const float* __restrict__ keys_in, const float* __restrict__ values,
    const float* __restrict__ W0, const float* __restrict__ b0,
    const float* __restrict__ W1, const float* __restrict__ b1,
    const float* __restrict__ W2, const float* __restrict__ b2,
    const float* __restrict__ W3, const float* __restrict__ b3,
    float* __restrict__ tbl, float2* __restrict__ pv_b,
    int* __restrict__ offs_b)
{
  const int tid = threadIdx.x;
  const int blk = blockIdx.x;

  if (blk < BB) {
    // ---- bucket batch `blk` by channel; store interleaved {pos, val} ----
    __shared__ int cnt[CC];
    __shared__ int offs[CC + 1];
    __shared__ int cur[CC];
    if (tid < CC) cnt[tid] = 0;
    __syncthreads();
    for (int k = tid; k < KK; k += 256) {
      int c = (int)keys_in[blk * (2 * KK) + 2 * k];
      atomicAdd(&cnt[c], 1);
    }
    __syncthreads();
    if (tid == 0) {
      int s = 0;
      for (int c = 0; c < CC; ++c) { offs[c] = s; cur[c] = s; s += cnt[c]; }
      offs[CC] = s;  // == 1024
    }
    __syncthreads();
    for (int k = tid; k < KK; k += 256) {
      int c = (int)keys_in[blk * (2 * KK) + 2 * k];
      float p = keys_in[blk * (2 * KK) + 2 * k + 1];
      int idx = atomicAdd(&cur[c], 1);
      pv_b[blk * KK + idx] = make_float2(p, values[(blk * KK + k) * CC + c]);
    }
    __syncthreads();
    if (tid < CC + 1) offs_b[blk * 32 + tid] = offs[tid];
  } else {
    // ---- build f(d,c) table ----
    __shared__ float sW0p[16];
    __shared__ float sH[256];       // hoh[c][i] = W0[i,1+c] + b0[i]
    __shared__ float sW1[256], sb1[16], sW2[256], sb2[16], sW3[16], sb3[1];
    if (tid < 16) {
      sW0p[tid] = W0[tid * 17];
      sb1[tid]  = b1[tid];
      sb2[tid]  = b2[tid];
      sW3[tid]  = W3[tid];
    }
    if (tid == 0) sb3[0] = b3[0];
    {
      int i = tid >> 4, c = tid & 15;
      sH[c * 16 + i] = W0[i * 17 + 1 + c] + b0[i];
      sW1[tid] = W1[tid];
      sW2[tid] = W2[tid];
    }
    __syncthreads();

    const int total = CC * (NS + 1);
    const int stride = (gridDim.x - BB) * 256;
    for (int e = (blk - BB) * 256 + tid; e < total; e += stride) {
      int c = e / (NS + 1);
      int s = e - c * (NS + 1);
      float d = (float)s * (0.25f / (float)NS);
      float h0[16], h1[16];
#pragma unroll
      for (int i = 0; i < 16; ++i) {
        float v = fmaf(d, sW0p[i], sH[c * 16 + i]);
        h0[i] = v > 0.f ? v : 0.f;
      }
#pragma unroll
      for (int j = 0; j < 16; ++j) {
        float a = sb1[j];
#pragma unroll
        for (int i = 0; i < 16; ++i) a = fmaf(sW1[j * 16 + i], h0[i], a);
        h1[j] = a > 0.f ? a : 0.f;
      }
      float w = sb3[0];
#pragma unroll
      for (int j = 0; j < 16; ++j) {
        float a = sb2[j];
#pragma unroll
        for (int i = 0; i < 16; ++i) a = fmaf(sW2[j * 16 + i], h1[i], a);
        a = a > 0.f ? a : 0.f;
        w = fmaf(sW3[j], a, w);
      }
      tbl[c * TSTRIDE + s] = fabsf(w);
    }
  }
}

// ---------------------------------------------------------------------------
// Kernel 2: 256 blocks (32/batch), 32 queries per block (8 per wave).
// lane = (c = lane&15, h = lane>>4); lane walks 1/4 of channel-c's bucket,
// reusing each key's {pos,val} across 8 queries. Table + keys + Wr all in
// LDS; inner loop is pure LDS+VALU, predicated (no divergent branch).
// Staging amortized 8x vs 4-query blocks: 256 x ~46 KB ~= 11.5 MB L2 reads.
// ---------------------------------------------------------------------------
__global__ __launch_bounds__(256) void main_kernel(
    const float* __restrict__ queries,
    const float* __restrict__ Wd, const float* __restrict__ bd,
    const float* __restrict__ Wr, const float* __restrict__ br,
    const float* __restrict__ tbl, const float2* __restrict__ pv_b,
    const int* __restrict__ offs_b,
    float* __restrict__ out)
{
  __shared__ float4 tls4[TFLOATS / 4];   // full f(d,c) table, 32832 B
  __shared__ float2 pv_s[KK];            // interleaved {pos, val}, 8192 B
  __shared__ int   offs_s[CC + 1];
  __shared__ float wr_s[32 * 33];        // padded stride 33
  __shared__ float br_s[32];
  __shared__ float ep_s[4][NQ][33];      // [wave][query][targets(16)|dens(16)]
  __shared__ float wdbd[2];
  float* tls = (float*)tls4;

  const int tid = threadIdx.x;
  const int b  = blockIdx.x >> 5;        // 32 blocks per batch
  const int qg = blockIdx.x & 31;        // 32 queries per block

  for (int i = tid; i < TFLOATS / 4; i += 256)
    tls4[i] = ((const float4*)tbl)[i];
  { // pv: 1024 float2 = 512 float4
    const float4* src = (const float4*)(pv_b + b * KK);
    float4* dst = (float4*)pv_s;
    for (int i = tid; i < KK / 2; i += 256) dst[i] = src[i];
  }
  if (tid < CC + 1) offs_s[tid] = offs_b[b * 32 + tid];
  { // Wr (32x32) into padded LDS
    int o = tid >> 5, j = tid & 31;
    wr_s[o * 33 + j] = Wr[tid];
    wr_s[(o + 8) * 33 + j]  = Wr[tid + 256];
    wr_s[(o + 16) * 33 + j] = Wr[tid + 512];
    wr_s[(o + 24) * 33 + j] = Wr[tid + 768];
  }
  if (tid < 32) br_s[tid] = br[tid];
  if (tid == 0) { wdbd[0] = Wd[0]; wdbd[1] = bd[0]; }
  __syncthreads();

  const int wave = tid >> 6;
  const int lane = tid & 63;
  const int q0 = qg * 32 + wave * NQ;    // first of this wave's 8 queries
  const int c = lane & 15;
  const int h = lane >> 4;

  float qpos[NQ];
#pragma unroll
  for (int j = 0; j < NQ; ++j) qpos[j] = queries[b * QQ + q0 + j];

  const float* __restrict__ tc = tls + c * TSTRIDE;
  float den[NQ], num[NQ];
#pragma unroll
  for (int j = 0; j < NQ; ++j) { den[j] = 0.f; num[j] = 0.f; }

  const int kend = offs_s[c + 1];
  for (int k = offs_s[c] + h; k < kend; k += 4) {
    float2 pv = pv_s[k];
    const float p = pv.x, v = pv.y;
#pragma unroll
    for (int j = 0; j < NQ; ++j) {
      float d = fabsf(p - qpos[j]);
      float t = d * ((float)NS / 0.25f);
      int   i = (int)t;
      i = i < NS - 1 ? i : NS - 1;
      float f = t - (float)i;
      float t0 = tc[i];
      float t1 = tc[i + 1];
      float w  = fmaf(t1 - t0, f, t0);
      w = (d < 0.25f) ? w : 0.0f;
      den[j] += w;
      num[j] = fmaf(w, v, num[j]);
    }
  }
#pragma unroll
  for (int j = 0; j < NQ; ++j) {
    den[j] += __shfl_xor(den[j], 16, 64);
    num[j] += __shfl_xor(num[j], 16, 64);
    den[j] += __shfl_xor(den[j], 32, 64);
    num[j] += __shfl_xor(num[j], 32, 64);
  }

  if (h == 0) {
#pragma unroll
    for (int j = 0; j < NQ; ++j) {
      float tgt = num[j] / (den[j] + 1e-5f);
      float x   = fmaf(fmaf(den[j], 0.1f, -1.0f), wdbd[0], wdbd[1]);
      float dn  = 1.0f / (1.0f + expf(-x));
      ep_s[wave][j][c]      = tgt;
      ep_s[wave][j][16 + c] = dn;
    }
  }
  __syncthreads();

  // epilogue: 8 queries x 32 outputs per wave; lane -> o = lane&31,
  // j = (lane>>5) + 2*jj. ep reads broadcast (1-2 addrs), wr_s stride-33.
  const int o = lane & 31;
#pragma unroll
  for (int jj = 0; jj < NQ / 2; ++jj) {
    const int j = (lane >> 5) + 2 * jj;
    float acc = br_s[o];
#pragma unroll
    for (int t = 0; t < 32; ++t)
      acc = fmaf(ep_s[wave][j][t], wr_s[o * 33 + t], acc);
    out[(b * QQ + q0 + j) * 32 + o] = acc;
  }
}

extern "C" void kernel_launch(void* const* d_in, const int* in_sizes, int n_in,
                              void* d_out, int out_size, void* d_ws, size_t ws_size,
                              hipStream_t stream) {
  const float* keys_in = (const float*)d_in[0];
  const float* queries = (const float*)d_in[1];
  const float* values  = (const float*)d_in[2];
  const float* W0 = (const float*)d_in[3];
  const float* b0 = (const float*)d_in[4];
  const float* W1 = (const float*)d_in[5];
  const float* b1 = (const float*)d_in[6];
  const float* W2 = (const float*)d_in[7];
  const float* b2 = (const float*)d_in[8];
  const float* W3 = (const float*)d_in[9];
  const float* b3 = (const float*)d_in[10];
  const float* Wd = (const float*)d_in[11];
  const float* bd = (const float*)d_in[12];
  const float* Wr = (const float*)d_in[13];
  const float* br = (const float*)d_in[14];
  float* out = (float*)d_out;

  // workspace layout (16B alignment maintained: TFLOATS*4 = 32832 B)
  float*  tbl   = (float*)d_ws;               // TFLOATS floats
  float2* pv_b  = (float2*)(tbl + TFLOATS);   // 8*1024 float2
  int*    offs_b = (int*)(pv_b + BB * KK);    // 8*32 ints

  prep_kernel<<<BB + 128, 256, 0, stream>>>(keys_in, values, W0, b0, W1, b1,
                                            W2, b2, W3, b3, tbl, pv_b, offs_b);
  main_kernel<<<256, 256, 0, stream>>>(queries, Wd, bd, Wr, br,
                                       tbl, pv_b, offs_b, out);
}